// Round 1
// baseline (5602.285 us; speedup 1.0000x reference)
//
#include <hip/hip_runtime.h>
#include <cstdint>
#include <cstddef>

typedef unsigned short ushort_t;
typedef __attribute__((ext_vector_type(4))) float f4;
typedef __attribute__((ext_vector_type(8))) short s8v;
typedef __attribute__((ext_vector_type(4))) short s4v;
typedef __attribute__((ext_vector_type(4))) unsigned short us4;

typedef const __attribute__((address_space(1))) void* gptr_t;
typedef __attribute__((address_space(3))) void* lptr_t;

#define DEV __device__ __forceinline__

enum { TT = 8192, HH = 2048, NHq = 16, NKVq = 8, DHq = 128, FF = 8192, SS = 1024, BBq = 8 };

DEV float bf2f(ushort_t u) { union { unsigned int i; float f; } x; x.i = ((unsigned int)u) << 16; return x.f; }
DEV ushort_t f2bf(float f) {
  union { float f; unsigned int i; } x; x.f = f;
  unsigned int r = x.i + 0x7fffu + ((x.i >> 16) & 1u);
  return (ushort_t)(r >> 16);
}

#define MFMA_BF16(a, b, c) __builtin_amdgcn_mfma_f32_16x16x32_bf16((a), (b), (c), 0, 0, 0)

// ---------------- RMSNorm over H=2048, one row per block (256 thr) ----------------
template <int BF16_OUT>
__global__ __launch_bounds__(256) void rms_kernel(const float* __restrict__ x,
                                                  const float* __restrict__ wgt,
                                                  void* __restrict__ out)
{
  __shared__ float red[4];
  const int t = threadIdx.x, lane = t & 63, w = t >> 6;
  const size_t row = blockIdx.x;
  const float* xr = x + row * HH;
  f4 v0 = *(const f4*)(xr + t * 4);
  f4 v1 = *(const f4*)(xr + 1024 + t * 4);
  float ss = v0[0]*v0[0] + v0[1]*v0[1] + v0[2]*v0[2] + v0[3]*v0[3]
           + v1[0]*v1[0] + v1[1]*v1[1] + v1[2]*v1[2] + v1[3]*v1[3];
#pragma unroll
  for (int off = 1; off < 64; off <<= 1) ss += __shfl_xor(ss, off);
  if (lane == 0) red[w] = ss;
  __syncthreads();
  const float tot = red[0] + red[1] + red[2] + red[3];
  const float r = rsqrtf(tot * (1.0f / (float)HH) + 1e-6f);
  f4 w0 = *(const f4*)(wgt + t * 4);
  f4 w1 = *(const f4*)(wgt + 1024 + t * 4);
  if (BF16_OUT) {
    ushort_t* ob = (ushort_t*)out;
    us4 a, b;
#pragma unroll
    for (int i = 0; i < 4; ++i) { a[i] = f2bf(v0[i] * r * w0[i]); b[i] = f2bf(v1[i] * r * w1[i]); }
    *(us4*)(ob + row * HH + t * 4) = a;
    *(us4*)(ob + row * HH + 1024 + t * 4) = b;
  } else {
    float* of = (float*)out;
    f4 a, b;
#pragma unroll
    for (int i = 0; i < 4; ++i) { a[i] = v0[i] * r * w0[i]; b[i] = v1[i] * r * w1[i]; }
    *(f4*)(of + row * HH + t * 4) = a;
    *(f4*)(of + row * HH + 1024 + t * 4) = b;
  }
}

// ---------------- fp32 [K][N] -> bf16 B^T [N][K] (32x32 LDS transpose) ----------------
__global__ __launch_bounds__(256) void wcvt_kernel(const float* __restrict__ w,
                                                   ushort_t* __restrict__ o, int K, int N)
{
  __shared__ float tile[32][33];
  const int t = threadIdx.x, ty = t >> 3, tx = t & 7;
  const int n0 = blockIdx.x * 32, k0 = blockIdx.y * 32;
  f4 ld = *(const f4*)(w + (size_t)(k0 + ty) * N + n0 + tx * 4);
#pragma unroll
  for (int i = 0; i < 4; ++i) tile[ty][tx * 4 + i] = ld[i];
  __syncthreads();
  us4 st;
#pragma unroll
  for (int i = 0; i < 4; ++i) st[i] = f2bf(tile[tx * 4 + i][ty]);
  *(us4*)(o + (size_t)(n0 + ty) * K + k0 + tx * 4) = st;
}

// ---------------- v [T][NKV][DH] bf16 -> vT [(b*NKV+kvh)][DH][S] ----------------
__global__ __launch_bounds__(256) void vtrans_kernel(const ushort_t* __restrict__ v,
                                                     ushort_t* __restrict__ vt)
{
  __shared__ ushort_t tile[32][40];
  const int t = threadIdx.x, ty = t >> 3, tx = t & 7;
  const int s0 = blockIdx.x * 32, d0 = blockIdx.y * 32;
  const int b = blockIdx.z >> 3, kvh = blockIdx.z & 7;
  us4 ld = *(const us4*)(v + ((size_t)(b * SS + s0 + ty) * NKVq + kvh) * DHq + d0 + tx * 4);
#pragma unroll
  for (int i = 0; i < 4; ++i) tile[ty][tx * 4 + i] = ld[i];
  __syncthreads();
  us4 st;
#pragma unroll
  for (int i = 0; i < 4; ++i) st[i] = tile[tx * 4 + i][ty];
  *(us4*)(vt + ((size_t)(b * NKVq + kvh) * DHq + d0 + ty) * SS + s0 + tx * 4) = st;
}

// ---------------- per-(token,head) RMS over DH=128 + RoPE (in place, bf16) ----------------
__global__ __launch_bounds__(256) void qkrope_kernel(ushort_t* __restrict__ buf,
                                                     const float* __restrict__ nw,
                                                     const int* __restrict__ pids,
                                                     int nh, float scale)
{
  const int w = threadIdx.x >> 6, lane = threadIdx.x & 63;
  const int idx = blockIdx.x * 4 + w;
  const int t = idx / nh;
  ushort_t* p = buf + (size_t)idx * DHq;
  float a = bf2f(p[lane]), b = bf2f(p[lane + 64]);
  float ss = a * a + b * b;
#pragma unroll
  for (int off = 1; off < 64; off <<= 1) ss += __shfl_xor(ss, off);
  const float r = rsqrtf(ss * (1.0f / (float)DHq) + 1e-6f);
  const float na = a * r * nw[lane], nb = b * r * nw[lane + 64];
  const float pos = (float)(pids[t] % SS);
  const float invf = expf((float)lane * -0.21586735246819178f);  // 1e6^(-lane/64)
  const float fr = pos * invf;
  const float c = cosf(fr), s = sinf(fr);
  p[lane]      = f2bf((na * c - nb * s) * scale);
  p[lane + 64] = f2bf((nb * c + na * s) * scale);
}

// ---------------- silu(g)*u elementwise, in place into g ----------------
__global__ __launch_bounds__(256) void silu_mul_kernel(ushort_t* __restrict__ g,
                                                       const ushort_t* __restrict__ u)
{
  const size_t i = ((size_t)blockIdx.x * 256 + threadIdx.x) * 4;
  us4 gv = *(const us4*)(g + i);
  us4 uv = *(const us4*)(u + i);
  us4 ov;
#pragma unroll
  for (int j = 0; j < 4; ++j) {
    float gf = bf2f(gv[j]), uf = bf2f(uv[j]);
    ov[j] = f2bf(gf / (1.0f + expf(-gf)) * uf);
  }
  *(us4*)(g + i) = ov;
}

// ---------------- GEMM: C[M,N] = A[M,K] * B^T[N,K]^T (bf16 in, fp32 acc) ----------------
// EPI 0: store bf16; EPI 1: fp32 C += (residual fused)
template <int EPI>
__global__ __launch_bounds__(256) void gemm_bt_kernel(
    const ushort_t* __restrict__ A, const ushort_t* __restrict__ BT,
    void* __restrict__ C, int M, int N, int K)
{
  __shared__ __attribute__((aligned(16))) ushort_t As[128 * 32];
  __shared__ __attribute__((aligned(16))) ushort_t Bs[128 * 32];
  const int t = threadIdx.x;
  const int lane = t & 63, w = t >> 6;
  const int lr = lane & 15, lq = lane >> 4;
  const int m0 = blockIdx.x * 128, n0 = blockIdx.y * 128;
  const int wm = (w >> 1) * 64, wn = (w & 1) * 64;

  f4 acc[4][4] = {};

  for (int kt = 0; kt < K; kt += 32) {
#pragma unroll
    for (int r = 0; r < 2; ++r) {
      const int idx = r * 256 + t;
      const int row = idx >> 2, col = (idx & 3) << 3;
      const ushort_t* ga = A + (size_t)(m0 + row) * K + kt + col;
      const ushort_t* gb = BT + (size_t)(n0 + row) * K + kt + col;
      __builtin_amdgcn_global_load_lds((gptr_t)ga, (lptr_t)(As + idx * 8), 16, 0, 0);
      __builtin_amdgcn_global_load_lds((gptr_t)gb, (lptr_t)(Bs + idx * 8), 16, 0, 0);
    }
    __syncthreads();
    s8v af[4], bf[4];
#pragma unroll
    for (int i = 0; i < 4; ++i) {
      af[i] = *(const s8v*)(As + (wm + i * 16 + lr) * 32 + lq * 8);
      bf[i] = *(const s8v*)(Bs + (wn + i * 16 + lr) * 32 + lq * 8);
    }
#pragma unroll
    for (int mi = 0; mi < 4; ++mi)
#pragma unroll
      for (int ni = 0; ni < 4; ++ni)
        acc[mi][ni] = MFMA_BF16(af[mi], bf[ni], acc[mi][ni]);
    __syncthreads();
  }

  if (EPI == 0) {
    ushort_t* Cb = (ushort_t*)C;
#pragma unroll
    for (int mi = 0; mi < 4; ++mi)
#pragma unroll
      for (int ni = 0; ni < 4; ++ni)
#pragma unroll
        for (int r = 0; r < 4; ++r)
          Cb[(size_t)(m0 + wm + mi * 16 + lq * 4 + r) * N + (n0 + wn + ni * 16 + lr)]
              = f2bf(acc[mi][ni][r]);
  } else {
    float* Cf = (float*)C;
#pragma unroll
    for (int mi = 0; mi < 4; ++mi)
#pragma unroll
      for (int ni = 0; ni < 4; ++ni)
#pragma unroll
        for (int r = 0; r < 4; ++r) {
          const size_t o = (size_t)(m0 + wm + mi * 16 + lq * 4 + r) * N + (n0 + wn + ni * 16 + lr);
          Cf[o] += acc[mi][ni][r];
        }
  }
}

// ---------------- Flash attention: S^T = K*Q^T formulation, one wave per 16-query strip ----
// q [T][NH][DH] (pre-normed, roped, pre-scaled), k [T][NKV][DH] (normed+roped),
// vt [(b*NKV+kvh)][DH][S], out attn [T][NH*DH]
__global__ __launch_bounds__(256) void flash_kernel(
    const ushort_t* __restrict__ q, const ushort_t* __restrict__ k,
    const ushort_t* __restrict__ vt, ushort_t* __restrict__ attn)
{
  __shared__ __attribute__((aligned(16))) ushort_t plds[4][16][32];
  const int w = threadIdx.x >> 6, lane = threadIdx.x & 63;
  const int lq = lane >> 4, lr = lane & 15;
  const int b = blockIdx.z, h = blockIdx.y, kvh = h >> 1;
  const int strip = blockIdx.x * 4 + w;
  const int q0 = strip * 16;

  s8v qf[4];
  const size_t qbase = ((size_t)(b * SS + q0 + lr) * NHq + h) * DHq;
#pragma unroll
  for (int kk = 0; kk < 4; ++kk)
    qf[kk] = *(const s8v*)(q + qbase + kk * 32 + lq * 8);

  f4 o[8] = {};
  float mprev = -3e38f, lsum = 0.0f;

  const int ntiles = (q0 + 15) / 32 + 1;
  const size_t vbase = (size_t)(b * NKVq + kvh) * DHq * SS;

  for (int kt = 0; kt < ntiles; ++kt) {
    const int k0 = kt * 32;
    f4 st[2] = {};
#pragma unroll
    for (int sub = 0; sub < 2; ++sub) {
      const size_t kbase = ((size_t)(b * SS + k0 + sub * 16 + lr) * NKVq + kvh) * DHq;
#pragma unroll
      for (int kk = 0; kk < 4; ++kk) {
        s8v kf = *(const s8v*)(k + kbase + kk * 32 + lq * 8);
        st[sub] = MFMA_BF16(kf, qf[kk], st[sub]);
      }
    }
    // mask + online softmax (per-query = per-column; column is lane&15)
    float sv[8], tmax = -3e38f;
#pragma unroll
    for (int sub = 0; sub < 2; ++sub)
#pragma unroll
      for (int r = 0; r < 4; ++r) {
        const int key = k0 + sub * 16 + lq * 4 + r;
        const float v = (key <= q0 + lr) ? st[sub][r] : -3e38f;
        sv[sub * 4 + r] = v;
        tmax = fmaxf(tmax, v);
      }
    tmax = fmaxf(tmax, __shfl_xor(tmax, 16));
    tmax = fmaxf(tmax, __shfl_xor(tmax, 32));
    const float mnew = fmaxf(mprev, tmax);
    const float alpha = expf(mprev - mnew);
    float psum = 0.0f;
    ushort_t pb[8];
#pragma unroll
    for (int i = 0; i < 8; ++i) {
      const float pv = expf(sv[i] - mnew);
      psum += pv;
      pb[i] = f2bf(pv);
    }
    psum += __shfl_xor(psum, 16);
    psum += __shfl_xor(psum, 32);
    lsum = lsum * alpha + psum;
    mprev = mnew;
#pragma unroll
    for (int i = 0; i < 8; ++i) o[i] *= alpha;

    // P^T round trip: plds[w][query][key 0..31]; read back as B-operand frag
    s4v p0 = { (short)pb[0], (short)pb[1], (short)pb[2], (short)pb[3] };
    s4v p1 = { (short)pb[4], (short)pb[5], (short)pb[6], (short)pb[7] };
    *(s4v*)(&plds[w][lr][lq * 4]) = p0;
    *(s4v*)(&plds[w][lr][16 + lq * 4]) = p1;
    s8v pf = *(const s8v*)(&plds[w][lr][lq * 8]);
#pragma unroll
    for (int dt = 0; dt < 8; ++dt) {
      s8v vf = *(const s8v*)(vt + vbase + (size_t)(dt * 16 + lr) * SS + k0 + lq * 8);
      o[dt] = MFMA_BF16(vf, pf, o[dt]);
    }
  }

  const float inv = 1.0f / lsum;
  const size_t obase = (size_t)(b * SS + q0 + lr) * (NHq * DHq) + h * DHq;
#pragma unroll
  for (int dt = 0; dt < 8; ++dt)
#pragma unroll
    for (int r = 0; r < 4; ++r)
      attn[obase + dt * 16 + lq * 4 + r] = f2bf(o[dt][r] * inv);
}

// ============================= host =============================
extern "C" void kernel_launch(void* const* d_in, const int* in_sizes, int n_in,
                              void* d_out, int out_size, void* d_ws, size_t ws_size,
                              hipStream_t stream)
{
  const float* hid = (const float*)d_in[0];
  const int* pids  = (const int*)d_in[1];
  const float* ln1 = (const float*)d_in[3];
  const float* qw  = (const float*)d_in[4];
  const float* kw  = (const float*)d_in[5];
  const float* vw  = (const float*)d_in[6];
  const float* ow  = (const float*)d_in[7];
  const float* qnw = (const float*)d_in[8];
  const float* knw = (const float*)d_in[9];
  const float* ln2 = (const float*)d_in[10];
  const float* gw  = (const float*)d_in[11];
  const float* uw  = (const float*)d_in[12];
  const float* dw  = (const float*)d_in[13];
  const float* fw  = (const float*)d_in[14];

  char* p = (char*)d_ws;
  ushort_t* wA  = (ushort_t*)p; p += (size_t)32 << 20;  // weight staging (q/o/gate)
  ushort_t* wB  = (ushort_t*)p; p += (size_t)32 << 20;  // weight staging (k/up)
  ushort_t* wC  = (ushort_t*)p; p += (size_t)32 << 20;  // weight staging (v/down)
  ushort_t* hb  = (ushort_t*)p; p += (size_t)32 << 20;  // normed hidden, bf16 [T][H]
  ushort_t* qb  = (ushort_t*)p; p += (size_t)32 << 20;  // q [T][NH][DH]
  ushort_t* kb  = (ushort_t*)p; p += (size_t)16 << 20;  // k [T][NKV][DH]
  ushort_t* vb  = (ushort_t*)p; p += (size_t)16 << 20;  // v [T][NKV][DH]
  ushort_t* vtb = (ushort_t*)p; p += (size_t)16 << 20;  // v^T [(b,kvh)][DH][S]
  ushort_t* ab  = (ushort_t*)p; p += (size_t)32 << 20;  // attn out [T][NH*DH]
  ushort_t* gb  = (ushort_t*)p; p += (size_t)32 << 20;  // gate chunk [2048][F]
  ushort_t* ub  = (ushort_t*)p; p += (size_t)32 << 20;  // up chunk [2048][F]
  if (ws_size < (size_t)(p - (char*)d_ws)) return;      // fail loudly (poisoned d_out)
  if (in_sizes[0] != TT * HH) return;

  float* x = (float*)d_out;  // fp32 residual stream lives in d_out
  hipMemcpyAsync(x, hid, (size_t)TT * HH * sizeof(float), hipMemcpyDeviceToDevice, stream);

  const float qscale = 0.08838834764831845f;  // 1/sqrt(128), folded into q

  for (int l = 0; l < 2; ++l) {
    rms_kernel<1><<<TT, 256, 0, stream>>>(x, ln1 + l * HH, hb);

    wcvt_kernel<<<dim3(64, 64), 256, 0, stream>>>(qw + (size_t)l * HH * 2048, wA, HH, 2048);
    gemm_bt_kernel<0><<<dim3(64, 16), 256, 0, stream>>>(hb, wA, qb, TT, 2048, HH);
    wcvt_kernel<<<dim3(32, 64), 256, 0, stream>>>(kw + (size_t)l * HH * 1024, wB, HH, 1024);
    gemm_bt_kernel<0><<<dim3(64, 8), 256, 0, stream>>>(hb, wB, kb, TT, 1024, HH);
    wcvt_kernel<<<dim3(32, 64), 256, 0, stream>>>(vw + (size_t)l * HH * 1024, wC, HH, 1024);
    gemm_bt_kernel<0><<<dim3(64, 8), 256, 0, stream>>>(hb, wC, vb, TT, 1024, HH);

    qkrope_kernel<<<TT * NHq / 4, 256, 0, stream>>>(qb, qnw + l * DHq, pids, NHq, qscale);
    qkrope_kernel<<<TT * NKVq / 4, 256, 0, stream>>>(kb, knw + l * DHq, pids, NKVq, 1.0f);
    vtrans_kernel<<<dim3(32, 4, 64), 256, 0, stream>>>(vb, vtb);
    flash_kernel<<<dim3(16, 16, 8), 256, 0, stream>>>(qb, kb, vtb, ab);

    wcvt_kernel<<<dim3(64, 64), 256, 0, stream>>>(ow + (size_t)l * 2048 * HH, wA, 2048, HH);
    gemm_bt_kernel<1><<<dim3(64, 16), 256, 0, stream>>>(ab, wA, x, TT, HH, 2048);

    rms_kernel<1><<<TT, 256, 0, stream>>>(x, ln2 + l * HH, hb);
    wcvt_kernel<<<dim3(256, 64), 256, 0, stream>>>(gw + (size_t)l * HH * FF, wA, HH, FF);
    wcvt_kernel<<<dim3(256, 64), 256, 0, stream>>>(uw + (size_t)l * HH * FF, wB, HH, FF);
    wcvt_kernel<<<dim3(64, 256), 256, 0, stream>>>(dw + (size_t)l * FF * HH, wC, FF, HH);
    for (int c = 0; c < 4; ++c) {
      const ushort_t* hc = hb + (size_t)c * 2048 * HH;
      gemm_bt_kernel<0><<<dim3(16, 64), 256, 0, stream>>>(hc, wA, gb, 2048, FF, HH);
      gemm_bt_kernel<0><<<dim3(16, 64), 256, 0, stream>>>(hc, wB, ub, 2048, FF, HH);
      silu_mul_kernel<<<16384, 256, 0, stream>>>(gb, ub);
      gemm_bt_kernel<1><<<dim3(16, 16), 256, 0, stream>>>(gb, wC, x + (size_t)c * 2048 * HH,
                                                          2048, HH, FF);
    }
  }
  rms_kernel<0><<<TT, 256, 0, stream>>>(x, fw, x);  // in place: d_out -> d_out
}

// Round 2
// 4915.512 us; speedup vs baseline: 1.1397x; 1.1397x over previous
//
#include <hip/hip_runtime.h>
#include <cstdint>
#include <cstddef>

typedef unsigned short ushort_t;
typedef __attribute__((ext_vector_type(4))) float f4;
typedef __attribute__((ext_vector_type(8))) short s8v;
typedef __attribute__((ext_vector_type(4))) short s4v;
typedef __attribute__((ext_vector_type(4))) unsigned short us4;

typedef const __attribute__((address_space(1))) void* gptr_t;
typedef __attribute__((address_space(3))) void* lptr_t;

#define DEV __device__ __forceinline__

enum { TT = 8192, HH = 2048, NHq = 16, NKVq = 8, DHq = 128, FF = 8192, SS = 1024, BBq = 8 };

DEV float bf2f(ushort_t u) { union { unsigned int i; float f; } x; x.i = ((unsigned int)u) << 16; return x.f; }
DEV ushort_t f2bf(float f) {
  union { float f; unsigned int i; } x; x.f = f;
  unsigned int r = x.i + 0x7fffu + ((x.i >> 16) & 1u);
  return (ushort_t)(r >> 16);
}

#define MFMA_BF16(a, b, c) __builtin_amdgcn_mfma_f32_16x16x32_bf16((a), (b), (c), 0, 0, 0)

// ---------------- RMSNorm over H=2048, one row per block (256 thr) ----------------
template <int BF16_OUT>
__global__ __launch_bounds__(256) void rms_kernel(const float* __restrict__ x,
                                                  const float* __restrict__ wgt,
                                                  void* __restrict__ out)
{
  __shared__ float red[4];
  const int t = threadIdx.x, lane = t & 63, w = t >> 6;
  const size_t row = blockIdx.x;
  const float* xr = x + row * HH;
  f4 v0 = *(const f4*)(xr + t * 4);
  f4 v1 = *(const f4*)(xr + 1024 + t * 4);
  float ss = v0[0]*v0[0] + v0[1]*v0[1] + v0[2]*v0[2] + v0[3]*v0[3]
           + v1[0]*v1[0] + v1[1]*v1[1] + v1[2]*v1[2] + v1[3]*v1[3];
#pragma unroll
  for (int off = 1; off < 64; off <<= 1) ss += __shfl_xor(ss, off);
  if (lane == 0) red[w] = ss;
  __syncthreads();
  const float tot = red[0] + red[1] + red[2] + red[3];
  const float r = rsqrtf(tot * (1.0f / (float)HH) + 1e-6f);
  f4 w0 = *(const f4*)(wgt + t * 4);
  f4 w1 = *(const f4*)(wgt + 1024 + t * 4);
  if (BF16_OUT) {
    ushort_t* ob = (ushort_t*)out;
    us4 a, b;
#pragma unroll
    for (int i = 0; i < 4; ++i) { a[i] = f2bf(v0[i] * r * w0[i]); b[i] = f2bf(v1[i] * r * w1[i]); }
    *(us4*)(ob + row * HH + t * 4) = a;
    *(us4*)(ob + row * HH + 1024 + t * 4) = b;
  } else {
    float* of = (float*)out;
    f4 a, b;
#pragma unroll
    for (int i = 0; i < 4; ++i) { a[i] = v0[i] * r * w0[i]; b[i] = v1[i] * r * w1[i]; }
    *(f4*)(of + row * HH + t * 4) = a;
    *(f4*)(of + row * HH + 1024 + t * 4) = b;
  }
}

// ---------------- fp32 [K][N] -> bf16 B^T [N][K] (32x32 LDS transpose) ----------------
__global__ __launch_bounds__(256) void wcvt_kernel(const float* __restrict__ w,
                                                   ushort_t* __restrict__ o, int K, int N)
{
  __shared__ float tile[32][33];
  const int t = threadIdx.x, ty = t >> 3, tx = t & 7;
  const int n0 = blockIdx.x * 32, k0 = blockIdx.y * 32;
  f4 ld = *(const f4*)(w + (size_t)(k0 + ty) * N + n0 + tx * 4);
#pragma unroll
  for (int i = 0; i < 4; ++i) tile[ty][tx * 4 + i] = ld[i];
  __syncthreads();
  us4 st;
#pragma unroll
  for (int i = 0; i < 4; ++i) st[i] = f2bf(tile[tx * 4 + i][ty]);
  *(us4*)(o + (size_t)(n0 + ty) * K + k0 + tx * 4) = st;
}

// ---------------- v [T][NKV][DH] bf16 -> vT [(b*NKV+kvh)][DH][S] ----------------
__global__ __launch_bounds__(256) void vtrans_kernel(const ushort_t* __restrict__ v,
                                                     ushort_t* __restrict__ vt)
{
  __shared__ ushort_t tile[32][40];
  const int t = threadIdx.x, ty = t >> 3, tx = t & 7;
  const int s0 = blockIdx.x * 32, d0 = blockIdx.y * 32;
  const int b = blockIdx.z >> 3, kvh = blockIdx.z & 7;
  us4 ld = *(const us4*)(v + ((size_t)(b * SS + s0 + ty) * NKVq + kvh) * DHq + d0 + tx * 4);
#pragma unroll
  for (int i = 0; i < 4; ++i) tile[ty][tx * 4 + i] = ld[i];
  __syncthreads();
  us4 st;
#pragma unroll
  for (int i = 0; i < 4; ++i) st[i] = tile[tx * 4 + i][ty];
  *(us4*)(vt + ((size_t)(b * NKVq + kvh) * DHq + d0 + ty) * SS + s0 + tx * 4) = st;
}

// ---------------- per-(token,head) RMS over DH=128 + RoPE (in place, bf16) ----------------
__global__ __launch_bounds__(256) void qkrope_kernel(ushort_t* __restrict__ buf,
                                                     const float* __restrict__ nw,
                                                     const int* __restrict__ pids,
                                                     int nh, float scale)
{
  const int w = threadIdx.x >> 6, lane = threadIdx.x & 63;
  const int idx = blockIdx.x * 4 + w;
  const int t = idx / nh;
  ushort_t* p = buf + (size_t)idx * DHq;
  float a = bf2f(p[lane]), b = bf2f(p[lane + 64]);
  float ss = a * a + b * b;
#pragma unroll
  for (int off = 1; off < 64; off <<= 1) ss += __shfl_xor(ss, off);
  const float r = rsqrtf(ss * (1.0f / (float)DHq) + 1e-6f);
  const float na = a * r * nw[lane], nb = b * r * nw[lane + 64];
  const float pos = (float)(pids[t] % SS);
  const float invf = exp2f((float)lane * -0.31143075889163463f);  // 1e6^(-lane/64)
  const float fr = pos * invf;
  const float c = cosf(fr), s = sinf(fr);
  p[lane]      = f2bf((na * c - nb * s) * scale);
  p[lane + 64] = f2bf((nb * c + na * s) * scale);
}

// ---------------- GEMM: C[M,N] = A[M,K] * B^T[N,K]^T (bf16 in, fp32 acc) ----------------
// EPI 0: store bf16; EPI 1: fp32 C += (residual fused); EPI 2: C = silu(Gsrc) * acc (bf16)
template <int EPI>
__global__ __launch_bounds__(256) void gemm_bt_kernel(
    const ushort_t* __restrict__ A, const ushort_t* __restrict__ BT,
    void* __restrict__ C, int M, int N, int K, const ushort_t* __restrict__ Gsrc)
{
  __shared__ __attribute__((aligned(16))) ushort_t As[128 * 32];
  __shared__ __attribute__((aligned(16))) ushort_t Bs[128 * 32];
  const int t = threadIdx.x;
  const int lane = t & 63, w = t >> 6;
  const int lr = lane & 15, lq = lane >> 4;
  const int m0 = blockIdx.x * 128, n0 = blockIdx.y * 128;
  const int wm = (w >> 1) * 64, wn = (w & 1) * 64;

  f4 acc[4][4] = {};

  for (int kt = 0; kt < K; kt += 32) {
#pragma unroll
    for (int r = 0; r < 2; ++r) {
      const int idx = r * 256 + t;
      const int row = idx >> 2, col = (idx & 3) << 3;
      const ushort_t* ga = A + (size_t)(m0 + row) * K + kt + col;
      const ushort_t* gb = BT + (size_t)(n0 + row) * K + kt + col;
      __builtin_amdgcn_global_load_lds((gptr_t)ga, (lptr_t)(As + idx * 8), 16, 0, 0);
      __builtin_amdgcn_global_load_lds((gptr_t)gb, (lptr_t)(Bs + idx * 8), 16, 0, 0);
    }
    __syncthreads();
    s8v af[4], bf[4];
#pragma unroll
    for (int i = 0; i < 4; ++i) {
      af[i] = *(const s8v*)(As + (wm + i * 16 + lr) * 32 + lq * 8);
      bf[i] = *(const s8v*)(Bs + (wn + i * 16 + lr) * 32 + lq * 8);
    }
#pragma unroll
    for (int mi = 0; mi < 4; ++mi)
#pragma unroll
      for (int ni = 0; ni < 4; ++ni)
        acc[mi][ni] = MFMA_BF16(af[mi], bf[ni], acc[mi][ni]);
    __syncthreads();
  }

  if (EPI == 0) {
    ushort_t* Cb = (ushort_t*)C;
#pragma unroll
    for (int mi = 0; mi < 4; ++mi)
#pragma unroll
      for (int ni = 0; ni < 4; ++ni)
#pragma unroll
        for (int r = 0; r < 4; ++r)
          Cb[(size_t)(m0 + wm + mi * 16 + lq * 4 + r) * N + (n0 + wn + ni * 16 + lr)]
              = f2bf(acc[mi][ni][r]);
  } else if (EPI == 1) {
    float* Cf = (float*)C;
#pragma unroll
    for (int mi = 0; mi < 4; ++mi)
#pragma unroll
      for (int ni = 0; ni < 4; ++ni)
#pragma unroll
        for (int r = 0; r < 4; ++r) {
          const size_t o = (size_t)(m0 + wm + mi * 16 + lq * 4 + r) * N + (n0 + wn + ni * 16 + lr);
          Cf[o] += acc[mi][ni][r];
        }
  } else {
    ushort_t* Cb = (ushort_t*)C;
#pragma unroll
    for (int mi = 0; mi < 4; ++mi)
#pragma unroll
      for (int ni = 0; ni < 4; ++ni)
#pragma unroll
        for (int r = 0; r < 4; ++r) {
          const size_t o = (size_t)(m0 + wm + mi * 16 + lq * 4 + r) * N + (n0 + wn + ni * 16 + lr);
          const float g = bf2f(Gsrc[o]);
          const float sg = g / (1.0f + exp2f(-g * 1.4426950408889634f));
          Cb[o] = f2bf(sg * acc[mi][ni][r]);
        }
  }
}

// ---------------- Flash attention v2: LDS-staged K/V tiles, S^T = K*Q^T ----------------
// Block: 64 queries (4 waves x 16-query strips) for one (b,h). K-tiles of 64 keys.
// q is pre-normed/roped/scaled by (1/sqrt(DH))*log2(e) -> softmax in exp2 domain.
// XOR-swizzled LDS layouts (swizzle applied on the GLOBAL address side of
// global_load_lds, since the LDS destination must be lane-contiguous).
__global__ __launch_bounds__(256) void flash_kernel(
    const ushort_t* __restrict__ q, const ushort_t* __restrict__ k,
    const ushort_t* __restrict__ vt, ushort_t* __restrict__ attn)
{
  __shared__ __attribute__((aligned(16))) ushort_t Ks[64 * 128];  // [key][dh], 16B-swizzled
  __shared__ __attribute__((aligned(16))) ushort_t Vs[128 * 64];  // [dh][key], 16B-swizzled
  __shared__ __attribute__((aligned(16))) ushort_t plds[4][16][64];  // per-wave P^T, swizzled
  const int t = threadIdx.x;
  const int w = t >> 6, lane = t & 63;
  const int lq = lane >> 4, lr = lane & 15;
  const int b = blockIdx.z, h = blockIdx.y, kvh = h >> 1;
  const int qtile = gridDim.x - 1 - blockIdx.x;  // heavy tiles dispatch first
  const int q0 = qtile * 64 + w * 16;

  s8v qf[4];
  const size_t qbase = ((size_t)(b * SS + q0 + lr) * NHq + h) * DHq;
#pragma unroll
  for (int kk = 0; kk < 4; ++kk)
    qf[kk] = *(const s8v*)(q + qbase + kk * 32 + lq * 8);

  f4 o[8] = {};
  float mprev = -3e38f, lsum = 0.0f;
  const int ntiles = qtile + 1;
  const size_t vbase = (size_t)(b * NKVq + kvh) * DHq * SS;

  for (int kt = 0; kt < ntiles; ++kt) {
    const int k0 = kt * 64;
    // stage K [64 keys][128 dh] and V^T [128 dh][64 keys], global-side swizzle
#pragma unroll
    for (int it = 0; it < 4; ++it) {
      const int idx = it * 256 + t;
      const int krow = idx >> 4, kcol = (((idx & 15) ^ (krow & 15)) << 3);
      const ushort_t* gk = k + ((size_t)(b * SS + k0 + krow) * NKVq + kvh) * DHq + kcol;
      __builtin_amdgcn_global_load_lds((gptr_t)gk, (lptr_t)(Ks + idx * 8), 16, 0, 0);
      const int vrow = idx >> 3, vcol = (((idx & 7) ^ (vrow & 7)) << 3);
      const ushort_t* gv = vt + vbase + (size_t)vrow * SS + k0 + vcol;
      __builtin_amdgcn_global_load_lds((gptr_t)gv, (lptr_t)(Vs + idx * 8), 16, 0, 0);
    }
    __syncthreads();

    // S^T = K * Q^T over 4 sub-tiles of 16 keys
    f4 st[4];
#pragma unroll
    for (int sub = 0; sub < 4; ++sub) {
      f4 s = {};
#pragma unroll
      for (int kk = 0; kk < 4; ++kk) {
        s8v kf = *(const s8v*)(Ks + (sub * 16 + lr) * 128 + (((kk * 4 + lq) ^ (lr & 15)) << 3));
        s = MFMA_BF16(kf, qf[kk], s);
      }
      st[sub] = s;
    }

    // causal mask + online softmax (query = lane&15 column; exp2 domain)
    float sv[16], tmax = -3e38f;
#pragma unroll
    for (int sub = 0; sub < 4; ++sub)
#pragma unroll
      for (int r = 0; r < 4; ++r) {
        const int key = k0 + sub * 16 + lq * 4 + r;
        const float v = (key <= q0 + lr) ? st[sub][r] : -3e38f;
        sv[sub * 4 + r] = v;
        tmax = fmaxf(tmax, v);
      }
    tmax = fmaxf(tmax, __shfl_xor(tmax, 16));
    tmax = fmaxf(tmax, __shfl_xor(tmax, 32));
    const float mnew = fmaxf(mprev, tmax);
    const float alpha = exp2f(mprev - mnew);
    float psum = 0.0f;
    ushort_t pb[16];
#pragma unroll
    for (int i = 0; i < 16; ++i) {
      const float pv = exp2f(sv[i] - mnew);
      psum += pv;
      pb[i] = f2bf(pv);
    }
    psum += __shfl_xor(psum, 16);
    psum += __shfl_xor(psum, 32);
    lsum = lsum * alpha + psum;
    mprev = mnew;
#pragma unroll
    for (int i = 0; i < 8; ++i) o[i] *= alpha;

    // P^T round-trip through per-wave LDS (swizzled by query row & 7)
#pragma unroll
    for (int sub = 0; sub < 4; ++sub) {
      s4v pv = { (short)pb[sub * 4 + 0], (short)pb[sub * 4 + 1],
                 (short)pb[sub * 4 + 2], (short)pb[sub * 4 + 3] };
      const int g = sub * 2 + (lq >> 1);
      *(s4v*)(&plds[w][lr][((g ^ (lr & 7)) << 3) + ((lq & 1) << 2)]) = pv;
    }
#pragma unroll
    for (int kq = 0; kq < 2; ++kq) {
      s8v pf = *(const s8v*)(&plds[w][lr][(((kq * 4 + lq) ^ (lr & 7)) << 3)]);
#pragma unroll
      for (int dt = 0; dt < 8; ++dt) {
        s8v vf = *(const s8v*)(Vs + (dt * 16 + lr) * 64 + (((kq * 4 + lq) ^ (lr & 7)) << 3));
        o[dt] = MFMA_BF16(vf, pf, o[dt]);
      }
    }
    __syncthreads();
  }

  const float inv = 1.0f / lsum;
  const size_t obase = (size_t)(b * SS + q0 + lr) * (NHq * DHq) + h * DHq;
#pragma unroll
  for (int dt = 0; dt < 8; ++dt)
#pragma unroll
    for (int r = 0; r < 4; ++r)
      attn[obase + dt * 16 + lq * 4 + r] = f2bf(o[dt][r] * inv);
}

// ============================= host =============================
extern "C" void kernel_launch(void* const* d_in, const int* in_sizes, int n_in,
                              void* d_out, int out_size, void* d_ws, size_t ws_size,
                              hipStream_t stream)
{
  const float* hid = (const float*)d_in[0];
  const int* pids  = (const int*)d_in[1];
  const float* ln1 = (const float*)d_in[3];
  const float* qw  = (const float*)d_in[4];
  const float* kw  = (const float*)d_in[5];
  const float* vw  = (const float*)d_in[6];
  const float* ow  = (const float*)d_in[7];
  const float* qnw = (const float*)d_in[8];
  const float* knw = (const float*)d_in[9];
  const float* ln2 = (const float*)d_in[10];
  const float* gw  = (const float*)d_in[11];
  const float* uw  = (const float*)d_in[12];
  const float* dw  = (const float*)d_in[13];
  const float* fw  = (const float*)d_in[14];

  char* p = (char*)d_ws;
  ushort_t* wA  = (ushort_t*)p; p += (size_t)32 << 20;  // weight staging (q/o/gate)
  ushort_t* wB  = (ushort_t*)p; p += (size_t)32 << 20;  // weight staging (k/up)
  ushort_t* wC  = (ushort_t*)p; p += (size_t)32 << 20;  // weight staging (v/down)
  ushort_t* hb  = (ushort_t*)p; p += (size_t)32 << 20;  // normed hidden, bf16 [T][H]
  ushort_t* qb  = (ushort_t*)p; p += (size_t)32 << 20;  // q [T][NH][DH]
  ushort_t* kb  = (ushort_t*)p; p += (size_t)16 << 20;  // k [T][NKV][DH]
  ushort_t* vb  = (ushort_t*)p; p += (size_t)16 << 20;  // v [T][NKV][DH]
  ushort_t* vtb = (ushort_t*)p; p += (size_t)16 << 20;  // v^T [(b,kvh)][DH][S]
  ushort_t* ab  = (ushort_t*)p; p += (size_t)32 << 20;  // attn out [T][NH*DH]
  ushort_t* gb  = (ushort_t*)p; p += (size_t)32 << 20;  // gate/silu-prod chunk [2048][F]
  if (ws_size < (size_t)(p - (char*)d_ws)) return;      // fail loudly (poisoned d_out)
  if (in_sizes[0] != TT * HH) return;

  float* x = (float*)d_out;  // fp32 residual stream lives in d_out
  hipMemcpyAsync(x, hid, (size_t)TT * HH * sizeof(float), hipMemcpyDeviceToDevice, stream);

  // 1/sqrt(128) * log2(e): softmax runs in exp2 domain inside flash
  const float qscale = 0.08838834764831845f * 1.4426950408889634f;

  for (int l = 0; l < 2; ++l) {
    rms_kernel<1><<<TT, 256, 0, stream>>>(x, ln1 + l * HH, hb);

    wcvt_kernel<<<dim3(64, 64), 256, 0, stream>>>(qw + (size_t)l * HH * 2048, wA, HH, 2048);
    gemm_bt_kernel<0><<<dim3(64, 16), 256, 0, stream>>>(hb, wA, qb, TT, 2048, HH, nullptr);
    wcvt_kernel<<<dim3(32, 64), 256, 0, stream>>>(kw + (size_t)l * HH * 1024, wB, HH, 1024);
    gemm_bt_kernel<0><<<dim3(64, 8), 256, 0, stream>>>(hb, wB, kb, TT, 1024, HH, nullptr);
    wcvt_kernel<<<dim3(32, 64), 256, 0, stream>>>(vw + (size_t)l * HH * 1024, wC, HH, 1024);
    gemm_bt_kernel<0><<<dim3(64, 8), 256, 0, stream>>>(hb, wC, vb, TT, 1024, HH, nullptr);

    qkrope_kernel<<<TT * NHq / 4, 256, 0, stream>>>(qb, qnw + l * DHq, pids, NHq, qscale);
    qkrope_kernel<<<TT * NKVq / 4, 256, 0, stream>>>(kb, knw + l * DHq, pids, NKVq, 1.0f);
    vtrans_kernel<<<dim3(32, 4, 64), 256, 0, stream>>>(vb, vtb);
    flash_kernel<<<dim3(16, 16, 8), 256, 0, stream>>>(qb, kb, vtb, ab);

    wcvt_kernel<<<dim3(64, 64), 256, 0, stream>>>(ow + (size_t)l * 2048 * HH, wA, 2048, HH);
    gemm_bt_kernel<1><<<dim3(64, 16), 256, 0, stream>>>(ab, wA, x, TT, HH, 2048, nullptr);

    rms_kernel<1><<<TT, 256, 0, stream>>>(x, ln2 + l * HH, hb);
    wcvt_kernel<<<dim3(256, 64), 256, 0, stream>>>(gw + (size_t)l * HH * FF, wA, HH, FF);
    wcvt_kernel<<<dim3(256, 64), 256, 0, stream>>>(uw + (size_t)l * HH * FF, wB, HH, FF);
    wcvt_kernel<<<dim3(64, 256), 256, 0, stream>>>(dw + (size_t)l * FF * HH, wC, FF, HH);
    for (int c = 0; c < 4; ++c) {
      const ushort_t* hc = hb + (size_t)c * 2048 * HH;
      gemm_bt_kernel<0><<<dim3(16, 64), 256, 0, stream>>>(hc, wA, gb, 2048, FF, HH, nullptr);
      gemm_bt_kernel<2><<<dim3(16, 64), 256, 0, stream>>>(hc, wB, gb, 2048, FF, HH, gb);
      gemm_bt_kernel<1><<<dim3(16, 16), 256, 0, stream>>>(gb, wC, x + (size_t)c * 2048 * HH,
                                                          2048, HH, FF, nullptr);
    }
  }
  rms_kernel<0><<<TT, 256, 0, stream>>>(x, fw, x);  // in place: d_out -> d_out
}